// Round 8
// baseline (449.352 us; speedup 1.0000x reference)
//
#include <hip/hip_runtime.h>

// Problem dims (fixed by reference setup_inputs)
constexpr int Bsz = 32768;
constexpr int Ksz = 4096;
constexpr int Dsz = 256;

constexpr int KD = 512;        // stored K-dim of split buffers [hi(256) | lo(256)]
constexpr int NT = 12;         // K-tiles of 64: 3 segment passes x 4
constexpr int NCAND = 16;      // 16 col-blocks of 256
constexpr int NFBLK = Bsz / 4; // finalize blocks (4 rows each)
constexpr float TAU = 1e-3f;   // top-2 gap below which finalize exact-compares in fp64

typedef __attribute__((ext_vector_type(8))) short short8;
typedef __attribute__((ext_vector_type(4))) float f32x4;

// --- fp32 -> bf16 (RNE) helpers ---------------------------------------------
__device__ __forceinline__ unsigned short f2bf(float f) {
  unsigned u = __float_as_uint(f);
  u += 0x7fffu + ((u >> 16) & 1u);
  return (unsigned short)(u >> 16);
}
__device__ __forceinline__ float bf2f(unsigned short h) {
  return __uint_as_float(((unsigned)h) << 16);
}

// ---------------------------------------------------------------------------
// Prep X: split fp32 rows into [hi | lo] bf16, row-major KD=512
// ---------------------------------------------------------------------------
__global__ __launch_bounds__(256) void vq_prep_x(const float* __restrict__ X,
                                                 unsigned short* __restrict__ X2) {
  const int tid = blockIdx.x * 256 + threadIdx.x;
  const int row = tid >> 6;
  const int d4 = tid & 63;
  const float4 v = *reinterpret_cast<const float4*>(X + (size_t)row * Dsz + d4 * 4);
  ushort4 h, l;
  h.x = f2bf(v.x); l.x = f2bf(v.x - bf2f(h.x));
  h.y = f2bf(v.y); l.y = f2bf(v.y - bf2f(h.y));
  h.z = f2bf(v.z); l.z = f2bf(v.z - bf2f(h.z));
  h.w = f2bf(v.w); l.w = f2bf(v.w - bf2f(h.w));
  *reinterpret_cast<ushort4*>(X2 + (size_t)row * KD + d4 * 4) = h;
  *reinterpret_cast<ushort4*>(X2 + (size_t)row * KD + 256 + d4 * 4) = l;
}

// ---------------------------------------------------------------------------
// Prep E: split + fp32 squared norms (wave per code row)
// ---------------------------------------------------------------------------
__global__ __launch_bounds__(256) void vq_prep_e(const float* __restrict__ E,
                                                 unsigned short* __restrict__ E2,
                                                 float* __restrict__ enorm) {
  const int wid = threadIdx.x >> 6;
  const int lane = threadIdx.x & 63;
  const int k = blockIdx.x * 4 + wid;
  const float4 v = *reinterpret_cast<const float4*>(E + (size_t)k * Dsz + lane * 4);
  ushort4 h, l;
  h.x = f2bf(v.x); l.x = f2bf(v.x - bf2f(h.x));
  h.y = f2bf(v.y); l.y = f2bf(v.y - bf2f(h.y));
  h.z = f2bf(v.z); l.z = f2bf(v.z - bf2f(h.z));
  h.w = f2bf(v.w); l.w = f2bf(v.w - bf2f(h.w));
  *reinterpret_cast<ushort4*>(E2 + (size_t)k * KD + lane * 4) = h;
  *reinterpret_cast<ushort4*>(E2 + (size_t)k * KD + 256 + lane * 4) = l;
  float s = v.x * v.x + v.y * v.y + v.z * v.z + v.w * v.w;
#pragma unroll
  for (int off = 32; off > 0; off >>= 1) s += __shfl_down(s, off);
  if (lane == 0) enorm[k] = s;
}

// ---------------------------------------------------------------------------
// Deep-pipelined 256x256 bf16 MFMA GEMM (flat Keff=768 over 12 BK=64 tiles:
// segments hi*hi, lo*hi, hi*lo via per-tile A/B offsets) + fused top-2 argmin.
// 512 thr (8 waves 2Mx4N, 128x64 per wave), double-buffered 128KB LDS,
// counted vmcnt(8) (loads in flight across barriers), setprio around MFMA.
// XOR slot-swizzle (slot ^= row&7) via pre-swizzled global source (0-conflict,
// verified round 6). cand[row][nb] = (m1,i1,m2,i2) after block-level merge.
// ---------------------------------------------------------------------------
__global__ __launch_bounds__(512, 2) void vq_gemm_argmin(
    const unsigned short* __restrict__ X2, const unsigned short* __restrict__ E2,
    const float* __restrict__ enorm, float4* __restrict__ cand) {
  __shared__ unsigned short sA[2][256 * 64];
  __shared__ unsigned short sB[2][256 * 64];

  const int t5 = threadIdx.x;
  const int lane = t5 & 63;
  const int wid = t5 >> 6;        // 0..7
  const int wm = wid >> 2;        // 0..1  (row half)
  const int wn = wid & 3;         // 0..3  (col quarter)

  // XCD-aware swizzle: 2048 blocks, XCD x owns a contiguous band of 16 mb
  const int bid = blockIdx.x;
  const int swz = (bid & 7) * 256 + (bid >> 3);
  const int mb = swz >> 4;        // 0..127
  const int nb = swz & 15;        // 0..15
  const int row0 = mb * 256;
  const int col0 = nb * 256;

  // staging: lane l writes LDS linearly at (r0 + l>>3)*128B + (l&7)*16B;
  // source fetches logical slot (l&7)^(l>>3) so swizzled reads see row-major.
  const int srow = lane >> 3;
  const int sslot = (lane & 7) ^ srow;

  // fragment read: row = base + l15 (row&7 == lane&7); k-slot = ks*4 + (l>>4)
  const int l15 = lane & 15;
  const int lhi = lane >> 4;
  const int lx = lane & 7;

  f32x4 acc[8][4];
#pragma unroll
  for (int m = 0; m < 8; ++m)
#pragma unroll
    for (int n = 0; n < 4; ++n) acc[m][n] = f32x4{0.f, 0.f, 0.f, 0.f};

  // per-tile K offsets (shorts) into [hi|lo]: passes hi*hi, lo*hi, hi*lo
#define AOF(kt) ((((kt) >> 2) == 1 ? 256 : 0) + ((kt) & 3) * 64)
#define BOF(kt) ((((kt) >> 2) == 2 ? 256 : 0) + ((kt) & 3) * 64)

#define STAGE(BUFI, AO, BO)                                                    \
  {                                                                            \
    _Pragma("unroll") for (int q = 0; q < 4; ++q) {                            \
      const int r = wid * 32 + q * 8;                                          \
      __builtin_amdgcn_global_load_lds(                                        \
          (const __attribute__((address_space(1))) void*)(                     \
              X2 + (size_t)(row0 + r + srow) * KD + (AO) + sslot * 8),         \
          (__attribute__((address_space(3))) void*)(&sA[BUFI][r * 64]), 16, 0, 0); \
    }                                                                          \
    _Pragma("unroll") for (int q = 0; q < 4; ++q) {                            \
      const int r = wid * 32 + q * 8;                                          \
      __builtin_amdgcn_global_load_lds(                                        \
          (const __attribute__((address_space(1))) void*)(                     \
              E2 + (size_t)(col0 + r + srow) * KD + (BO) + sslot * 8),         \
          (__attribute__((address_space(3))) void*)(&sB[BUFI][r * 64]), 16, 0, 0); \
    }                                                                          \
  }

#define LOADFRAGS(BUFI, KS)                                                    \
  {                                                                            \
    _Pragma("unroll") for (int m = 0; m < 8; ++m)                              \
        af[m] = *reinterpret_cast<const short8*>(                              \
            &sA[BUFI][(wm * 128 + m * 16 + l15) * 64 +                         \
                      (((KS)*4 + lhi) ^ lx) * 8]);                             \
    _Pragma("unroll") for (int n = 0; n < 4; ++n)                              \
        bf[n] = *reinterpret_cast<const short8*>(                              \
            &sB[BUFI][(wn * 64 + n * 16 + l15) * 64 +                          \
                      (((KS)*4 + lhi) ^ lx) * 8]);                             \
  }

#define MFMAS                                                                  \
  {                                                                            \
    _Pragma("unroll") for (int m = 0; m < 8; ++m)                              \
        _Pragma("unroll") for (int n = 0; n < 4; ++n)                          \
            acc[m][n] = __builtin_amdgcn_mfma_f32_16x16x32_bf16(               \
                af[m], bf[n], acc[m][n], 0, 0, 0);                             \
  }

  // prologue: two tiles in flight (16 loads/wave)
  STAGE(0, AOF(0), BOF(0));
  STAGE(1, AOF(1), BOF(1));

#pragma unroll
  for (int t = 0; t < NT; ++t) {
    const int buf = t & 1;
    short8 af[8], bf[4];

    if (t < NT - 1) {
      asm volatile("s_waitcnt vmcnt(8)" ::: "memory");  // tile t landed; t+1 in flight
    } else {
      asm volatile("s_waitcnt vmcnt(0)" ::: "memory");  // final drain
    }
    __builtin_amdgcn_sched_barrier(0);
    __builtin_amdgcn_s_barrier();        // B1: buf[t&1] ready for all waves
    __builtin_amdgcn_sched_barrier(0);

    // k-phase 0
    LOADFRAGS(buf, 0);
    asm volatile("s_waitcnt lgkmcnt(0)" ::: "memory");
    __builtin_amdgcn_sched_barrier(0);
    __builtin_amdgcn_s_setprio(1);
    MFMAS;
    __builtin_amdgcn_s_setprio(0);

    // k-phase 1 reads
    LOADFRAGS(buf, 1);
    asm volatile("s_waitcnt lgkmcnt(0)" ::: "memory");
    __builtin_amdgcn_sched_barrier(0);
    __builtin_amdgcn_s_barrier();        // B2: all waves done reading buf
    __builtin_amdgcn_sched_barrier(0);

    if (t + 2 < NT) {                    // prefetch tile t+2 into freed buf
      STAGE(buf, AOF(t + 2), BOF(t + 2));
    }
    __builtin_amdgcn_sched_barrier(0);

    __builtin_amdgcn_s_setprio(1);
    MFMAS;                               // k-phase 1 compute overlaps prefetch
    __builtin_amdgcn_s_setprio(0);
  }

  // ------------------------ fused argmin epilogue --------------------------
  __syncthreads();

  float en[4];
#pragma unroll
  for (int n = 0; n < 4; ++n) en[n] = enorm[col0 + wn * 64 + n * 16 + l15];

  float4* scr = reinterpret_cast<float4*>(&sA[0][0]);  // [256][4] = 16KB

#pragma unroll
  for (int m = 0; m < 8; ++m) {
#pragma unroll
    for (int q = 0; q < 4; ++q) {
      float v1 = 3.4e38f, v2 = 3.4e38f;
      int ii1 = 0x7fffffff, ii2 = 0x7fffffff;
#pragma unroll
      for (int n = 0; n < 4; ++n) {
        const float s = en[n] - 2.0f * acc[m][n][q];
        const int colg = col0 + wn * 64 + n * 16 + l15;
        if (s < v1) { v2 = v1; ii2 = ii1; v1 = s; ii1 = colg; }
        else if (s < v2) { v2 = s; ii2 = colg; }
      }
#pragma unroll
      for (int mbit = 1; mbit <= 8; mbit <<= 1) {
        const float ov1 = __shfl_xor(v1, mbit);
        const float ov2 = __shfl_xor(v2, mbit);
        const int oi1 = __shfl_xor(ii1, mbit);
        const int oi2 = __shfl_xor(ii2, mbit);
        if (ov1 < v1 || (ov1 == v1 && oi1 < ii1)) {
          float nv2 = v1; int ni2 = ii1;
          if (ov2 < nv2) { nv2 = ov2; ni2 = oi2; }
          v1 = ov1; ii1 = oi1; v2 = nv2; ii2 = ni2;
        } else if (ov1 < v2) {
          v2 = ov1; ii2 = oi1;
        }
      }
      if (l15 == 0) {
        const int rl = wm * 128 + m * 16 + lhi * 4 + q;
        scr[rl * 4 + wn] = make_float4(v1, __int_as_float(ii1),
                                       v2, __int_as_float(ii2));
      }
    }
  }
  __syncthreads();
  if (t5 < 256) {
    float v1 = 3.4e38f, v2 = 3.4e38f;
    int ii1 = 0x7fffffff, ii2 = 0x7fffffff;
#pragma unroll
    for (int j = 0; j < 4; ++j) {
      const float4 c = scr[t5 * 4 + j];
      const float o1 = c.x, o2 = c.z;
      const int a1 = __float_as_int(c.y), a2 = __float_as_int(c.w);
      if (o1 < v1 || (o1 == v1 && a1 < ii1)) {
        float nv2 = v1; int ni2 = ii1;
        if (o2 < nv2) { nv2 = o2; ni2 = a2; }
        v2 = nv2; ii2 = ni2; v1 = o1; ii1 = a1;
      } else if (o1 < v2) {
        v2 = o1; ii2 = a1;
      }
    }
    cand[(size_t)(row0 + t5) * NCAND + nb] =
        make_float4(v1, __int_as_float(ii1), v2, __int_as_float(ii2));
  }
#undef AOF
#undef BOF
#undef STAGE
#undef LOADFRAGS
#undef MFMAS
}

// ---------------------------------------------------------------------------
// Finalize: merge 16 candidates per row; if top-2 gap < TAU, exact fp64 compare
// of the two codes. Gather, write quantized + index; block loss partial.
// ---------------------------------------------------------------------------
__global__ __launch_bounds__(256) void vq_finalize(
    const float* __restrict__ X, const float* __restrict__ E,
    const float4* __restrict__ cand, float* __restrict__ out,
    float* __restrict__ partial) {
  __shared__ float ls[4];
  const int wid = threadIdx.x >> 6;
  const int lane = threadIdx.x & 63;
  const int b = blockIdx.x * 4 + wid;

  float v1 = 3.4e38f, v2 = 3.4e38f;
  int ii1 = 0x7fffffff, ii2 = 0x7fffffff;
  if (lane < NCAND) {
    const float4 c = cand[(size_t)b * NCAND + lane];
    v1 = c.x; ii1 = __float_as_int(c.y);
    v2 = c.z; ii2 = __float_as_int(c.w);
  }
#pragma unroll
  for (int mbit = 1; mbit <= 8; mbit <<= 1) {
    const float ov1 = __shfl_xor(v1, mbit);
    const float ov2 = __shfl_xor(v2, mbit);
    const int oi1 = __shfl_xor(ii1, mbit);
    const int oi2 = __shfl_xor(ii2, mbit);
    if (ov1 < v1 || (ov1 == v1 && oi1 < ii1)) {
      float nv2 = v1; int ni2 = ii1;
      if (ov2 < nv2) { nv2 = ov2; ni2 = oi2; }
      v1 = ov1; ii1 = oi1; v2 = nv2; ii2 = ni2;
    } else if (ov1 < v2) {
      v2 = ov1; ii2 = oi1;
    }
  }
  v1 = __shfl(v1, 0); v2 = __shfl(v2, 0);
  ii1 = __shfl(ii1, 0); ii2 = __shfl(ii2, 0);

  const float4 x = *reinterpret_cast<const float4*>(X + (size_t)b * Dsz + lane * 4);

  if (v2 - v1 < TAU) {
    const float4 e1 = *reinterpret_cast<const float4*>(E + (size_t)ii1 * Dsz + lane * 4);
    const float4 e2 = *reinterpret_cast<const float4*>(E + (size_t)ii2 * Dsz + lane * 4);
    double d1 = ((double)x.x - e1.x) * ((double)x.x - e1.x) +
                ((double)x.y - e1.y) * ((double)x.y - e1.y) +
                ((double)x.z - e1.z) * ((double)x.z - e1.z) +
                ((double)x.w - e1.w) * ((double)x.w - e1.w);
    double d2 = ((double)x.x - e2.x) * ((double)x.x - e2.x) +
                ((double)x.y - e2.y) * ((double)x.y - e2.y) +
                ((double)x.z - e2.z) * ((double)x.z - e2.z) +
                ((double)x.w - e2.w) * ((double)x.w - e2.w);
#pragma unroll
    for (int mbit = 1; mbit <= 32; mbit <<= 1) {
      d1 += __shfl_xor(d1, mbit);
      d2 += __shfl_xor(d2, mbit);
    }
    if (d2 < d1 || (d2 == d1 && ii2 < ii1)) ii1 = ii2;
  }

  const float4 q = *reinterpret_cast<const float4*>(E + (size_t)ii1 * Dsz + lane * 4);
  *reinterpret_cast<float4*>(out + (size_t)b * Dsz + lane * 4) = q;

  const float dx = x.x - q.x, dy = x.y - q.y, dz = x.z - q.z, dw = x.w - q.w;
  float s2 = dx * dx + dy * dy + dz * dz + dw * dw;
#pragma unroll
  for (int off = 32; off > 0; off >>= 1) s2 += __shfl_down(s2, off);
  if (lane == 0) {
    ls[wid] = s2;
    out[(size_t)Bsz * Dsz + 1 + b] = (float)ii1;
  }
  __syncthreads();
  if (threadIdx.x == 0)
    partial[blockIdx.x] = ls[0] + ls[1] + ls[2] + ls[3];
}

// ---------------------------------------------------------------------------
// Loss reduce: one block sums the per-block partials -> out[B*D]
// ---------------------------------------------------------------------------
__global__ __launch_bounds__(256) void vq_loss_reduce(const float* __restrict__ partial,
                                                      float* __restrict__ out) {
  __shared__ float ls[4];
  const int wid = threadIdx.x >> 6;
  const int lane = threadIdx.x & 63;
  float s = 0.f;
  for (int i = threadIdx.x; i < NFBLK; i += 256) s += partial[i];
#pragma unroll
  for (int off = 32; off > 0; off >>= 1) s += __shfl_down(s, off);
  if (lane == 0) ls[wid] = s;
  __syncthreads();
  if (threadIdx.x == 0)
    out[(size_t)Bsz * Dsz] = (ls[0] + ls[1] + ls[2] + ls[3]) *
                             (1.25f / ((float)Bsz * (float)Dsz));
}

// ---------------------------------------------------------------------------
extern "C" void kernel_launch(void* const* d_in, const int* in_sizes, int n_in,
                              void* d_out, int out_size, void* d_ws, size_t ws_size,
                              hipStream_t stream) {
  const float* X = (const float*)d_in[0];  // [B, D] fp32
  const float* E = (const float*)d_in[1];  // [K, D] fp32
  float* out = (float*)d_out;

  char* ws = (char*)d_ws;
  float* enorm = (float*)ws;                                             // 16 KB
  unsigned short* X2 = (unsigned short*)(ws + (16 << 10));               // 32 MB
  unsigned short* E2 = (unsigned short*)(ws + (16 << 10) + (32 << 20));  // 4 MB
  float4* cand = (float4*)(ws + (16 << 10) + (36 << 20));                // 8 MB
  float* partial = (float*)(ws + (16 << 10) + (44 << 20));               // 32 KB

  vq_prep_x<<<Bsz * 64 / 256, 256, 0, stream>>>(X, X2);
  vq_prep_e<<<Ksz / 4, 256, 0, stream>>>(E, E2, enorm);
  vq_gemm_argmin<<<(Bsz / 256) * (Ksz / 256), 512, 0, stream>>>(X2, E2, enorm, cand);
  vq_finalize<<<NFBLK, 256, 0, stream>>>(X, E, cand, out, partial);
  vq_loss_reduce<<<1, 256, 0, stream>>>(partial, out);
}